// Round 11
// baseline (208.195 us; speedup 1.0000x reference)
//
#include <hip/hip_runtime.h>
#include <stdint.h>

// SeqAttnMatch: B=32, LP=2048, LQ=512, D=256, fp32 in/out. Single-plane fp16 pipeline.
// k_attn: 64 rows/block, 4 waves, lb(256,2). Each wave owns ALL 4 row-tiles ->
// 4 MFMAs per loaded B-frag (2x arithmetic intensity), half the L2 traffic.
#define B_  32
#define LP_ 2048
#define LQ_ 512
#define D_  256

typedef __attribute__((ext_vector_type(8))) short short8;      // 8 x 16-bit
typedef __attribute__((ext_vector_type(8))) _Float16 f16x8;    // MFMA A/B frag (4 VGPRs)
typedef __attribute__((ext_vector_type(4))) float f32x4;

__device__ __forceinline__ ushort f2h(float x) {
    union { _Float16 h; ushort u; } v;
    v.h = (_Float16)x;                 // RNE convert
    return v.u;
}
// async global->LDS, 16B/lane; HW writes lds_base + lane*16 (wave-uniform base).
__device__ __forceinline__ void gl_lds16(const void* g, void* l) {
    __builtin_amdgcn_global_load_lds(
        (const __attribute__((address_space(1))) void*)g,
        (__attribute__((address_space(3))) void*)l, 16, 0, 0);
}

// Fragment-blocked layout: 1KB blocks of 512 ushorts. Element for lane
// L=quad*16+c, position L*8 + j, holds M[row_tile*16 + c][k0 + quad*8 + j].

// ---- K0: fused W f32->f16 frag convert (blocks 0..255) + y transpose (256..767) ----
__global__ void k_prep(const float* __restrict__ W, const float* __restrict__ y,
                       ushort* __restrict__ Whf, ushort* __restrict__ yf) {
    __shared__ float t[32 * 260];
    if (blockIdx.x < 256) {
        int i = blockIdx.x * 256 + threadIdx.x;
        int e = i >> 8, k = i & 255;
        size_t off = (size_t)((k >> 5) * 16 + (e >> 4)) * 512 +
                     ((k >> 3) & 3) * 128 + (e & 15) * 8 + (k & 7);
        Whf[off] = f2h(W[i]);
        return;
    }
    int bid = blockIdx.x - 256;      // 512 blocks
    int b = bid >> 4, qc = bid & 15;
    int tid = threadIdx.x;
    int ql = tid >> 3;               // 0..31
    int d0 = (tid & 7) * 4;
#pragma unroll
    for (int p = 0; p < 8; p++) {
        int d = p * 32 + d0;
        float4 v = *(const float4*)(y + ((size_t)(b * LQ_ + qc * 32 + ql) * 256 + d));
        t[ql * 260 + d + 0] = v.x; t[ql * 260 + d + 1] = v.y;
        t[ql * 260 + d + 2] = v.z; t[ql * 260 + d + 3] = v.w;
    }
    __syncthreads();
    int w = tid >> 6, L = tid & 63, c = L & 15, quad = L >> 4;
#pragma unroll
    for (int ii = 0; ii < 4; ii++) {
        int nt = w * 4 + ii;
        short8 o;
#pragma unroll
        for (int j = 0; j < 8; j++)
            o[j] = (short)f2h(t[(quad * 8 + j) * 260 + nt * 16 + c]);
        *(short8*)(yf + ((size_t)(b * 256 + qc * 16 + nt) * 512 + L * 8)) = o;
    }
}

// ---- K1: y-proj = relu(y @ W^T + b) -> frag-blocked f16 (256 blocks, 64 rows each) ----
__global__ __launch_bounds__(256, 3) void k_proj(const float* __restrict__ y,
                                                 const ushort* __restrict__ Whf,
                                                 const float* __restrict__ bias,
                                                 ushort* __restrict__ Oy) {
    __shared__ __align__(16) ushort Ws[16704];   // 32KB ping-pong, then 33.3KB transpose
    const int tid  = threadIdx.x;
    const int w    = tid >> 6;
    const int L    = tid & 63;
    const int c    = L & 15;
    const int quad = L >> 4;
    const int row0 = blockIdx.x * 64 + w * 16;
    const int arow = row0 + c;

    f32x4 acc[16];
#pragma unroll
    for (int i = 0; i < 16; i++) acc[i] = (f32x4)0.f;

#define PSTAGE(kc, p)                                                          \
    {                                                                          \
        _Pragma("unroll")                                                      \
        for (int ii = 0; ii < 4; ii++) {                                       \
            int i = w * 4 + ii;                                                \
            gl_lds16(Whf + (size_t)(kc) * 8192 + i * 512 + L * 8,              \
                     (char*)Ws + (p) * 16384 + i * 1024);                      \
        }                                                                      \
    }

    PSTAGE(0, 0);
    float4 nx0 = *(const float4*)(y + (size_t)arow * 256 + quad * 8);
    float4 nx1 = *(const float4*)(y + (size_t)arow * 256 + quad * 8 + 4);

    for (int kc = 0; kc < 8; kc++) {
        __syncthreads();
        if (kc < 7) PSTAGE(kc + 1, (kc + 1) & 1);
        float4 cx0 = nx0, cx1 = nx1;
        if (kc < 7) {
            nx0 = *(const float4*)(y + (size_t)arow * 256 + (kc + 1) * 32 + quad * 8);
            nx1 = *(const float4*)(y + (size_t)arow * 256 + (kc + 1) * 32 + quad * 8 + 4);
        }
        float xs[8] = {cx0.x, cx0.y, cx0.z, cx0.w, cx1.x, cx1.y, cx1.z, cx1.w};
        f16x8 ah;
#pragma unroll
        for (int j = 0; j < 8; j++) ah[j] = (_Float16)xs[j];
        const ushort* buf = Ws + (kc & 1) * 8192;
#pragma unroll
        for (int nt = 0; nt < 16; nt++) {
            f16x8 bh = *(const f16x8*)(buf + nt * 512 + L * 8);
            acc[nt] = __builtin_amdgcn_mfma_f32_16x16x32_f16(ah, bh, acc[nt], 0, 0, 0);
        }
    }

    // epilogue: bias+relu, per-wave LDS transpose C-layout -> B-frag layout
    __syncthreads();                 // all waves done reading Ws
    float* tr = (float*)Ws + w * (16 * 130);
    const int rt_g = row0 >> 4;
#pragma unroll
    for (int half = 0; half < 2; half++) {
#pragma unroll
        for (int nt8 = 0; nt8 < 8; nt8++) {
            int nt = half * 8 + nt8;
            float bv = bias[nt * 16 + c];
#pragma unroll
            for (int r = 0; r < 4; r++)
                tr[(quad * 4 + r) * 130 + nt8 * 16 + c] = fmaxf(acc[nt][r] + bv, 0.f);
        }
#pragma unroll
        for (int ec4 = 0; ec4 < 4; ec4++) {
            int ec = half * 4 + ec4;
            short8 hh;
#pragma unroll
            for (int j = 0; j < 8; j++)
                hh[j] = (short)f2h(tr[c * 130 + ec4 * 32 + quad * 8 + j]);
            size_t blk = (size_t)(rt_g >> 5) * 256 + ec * 32 + (rt_g & 31);
            *(short8*)(Oy + blk * 512 + L * 8) = hh;
        }
    }
}

// ---- K2: fused x-proj + scores + softmax + match. 64 rows/block, 1024 blocks. ----
// LDS 64KB (ushort idx): [0,16384) x-frags (32 units rt*8+kc) -> red -> alpha lo;
// [16384,32768) pfrag (32 units) -> alpha hi. Alpha = [64 rows][512 q] f16.
// Wave w = q-quarter (A) / d-quarter (C) / e-quarter (proj), ALL 4 row-tiles.
__global__ __launch_bounds__(256, 2) void k_attn(const float* __restrict__ x,
                                                 const ushort* __restrict__ Whf,
                                                 const float* __restrict__ bias,
                                                 const ushort* __restrict__ ypf,
                                                 const ushort* __restrict__ yf,
                                                 float* __restrict__ out) {
    __shared__ __align__(16) ushort lds[32768];   // 64KB
    const int tid  = threadIdx.x;
    const int w    = tid >> 6;
    const int L    = tid & 63;
    const int c    = L & 15;
    const int quad = L >> 4;

    // XCD-affinity swizzle: XCD x sees only batches 4x..4x+3
    const int bid = blockIdx.x;      // 1024
    const int jj  = bid >> 3;        // 0..127
    const int b   = (bid & 7) * 4 + (jj >> 5);
    const int mt  = jj & 31;         // 0..31, 64 rows each
    const int m0  = mt * 64;

    // ---- stage x A-frags (inline f32->f16): 32 units (rt*8+kc) x 1KB ----
#pragma unroll
    for (int ii = 0; ii < 8; ii++) {
        int unit = w * 8 + ii;
        int rt = unit >> 3, kc = unit & 7;
        const float* xs = x + ((size_t)(b * LP_ + m0 + rt * 16 + c)) * 256 + kc * 32 + quad * 8;
        float4 v0 = *(const float4*)xs;
        float4 v1 = *(const float4*)(xs + 4);
        f16x8 h;
        h[0] = (_Float16)v0.x; h[1] = (_Float16)v0.y;
        h[2] = (_Float16)v0.z; h[3] = (_Float16)v0.w;
        h[4] = (_Float16)v1.x; h[5] = (_Float16)v1.y;
        h[6] = (_Float16)v1.z; h[7] = (_Float16)v1.w;
        *(f16x8*)(lds + unit * 512 + L * 8) = h;
    }
    __syncthreads();                 // x-frags visible

    // ---- x-proj: wave w = e-quarter (4 nt) x ALL 4 row-tiles (4 MFMA/Whf-load) ----
    {
        float bv[4];
#pragma unroll
        for (int ne = 0; ne < 4; ne++) bv[ne] = bias[(w * 4 + ne) * 16 + c];
        f32x4 pacc[4][4];
#pragma unroll
        for (int rt = 0; rt < 4; rt++)
#pragma unroll
            for (int ne = 0; ne < 4; ne++) pacc[rt][ne] = (f32x4)0.f;
        for (int kc = 0; kc < 8; kc++) {
            f16x8 wb[4];
#pragma unroll
            for (int ne = 0; ne < 4; ne++)
                wb[ne] = *(const f16x8*)(Whf + ((size_t)(kc * 16 + w * 4 + ne)) * 512 + L * 8);
#pragma unroll
            for (int rt = 0; rt < 4; rt++) {
                f16x8 ah = *(const f16x8*)(lds + (rt * 8 + kc) * 512 + L * 8);
#pragma unroll
                for (int ne = 0; ne < 4; ne++)
                    pacc[rt][ne] = __builtin_amdgcn_mfma_f32_16x16x32_f16(ah, wb[ne], pacc[rt][ne], 0, 0, 0);
            }
        }
        // scatter relu(acc+bias) f16 -> pfrag [16384,32768) in A-frag layout.
        // e = (w*4+ne)*16+c; unit = rt*8 + (e>>5) = rt*8 + w*2+(ne>>1).
#pragma unroll
        for (int rt = 0; rt < 4; rt++)
#pragma unroll
            for (int ne = 0; ne < 4; ne++) {
#pragma unroll
                for (int r = 0; r < 4; r++) {
                    float v = fmaxf(pacc[rt][ne][r] + bv[ne], 0.f);
                    int off = 16384 + (rt * 8 + w * 2 + (ne >> 1)) * 512 +
                              ((ne & 1) * 2 + (c >> 3)) * 128 + (quad * 4 + r) * 8 + (c & 7);
                    lds[off] = f2h(v);
                }
            }
    }

    f32x4 sc[4][8];
#pragma unroll
    for (int rt = 0; rt < 4; rt++)
#pragma unroll
        for (int qt = 0; qt < 8; qt++) sc[rt][qt] = (f32x4)0.f;
    __syncthreads();                 // pfrag visible

    // ---- Phase A: barrier-free; wave w = q-quarter, 4 MFMA per ypf load ----
    const ushort* pf = lds + 16384;
    const ushort* yb = ypf + (size_t)b * 256 * 512;
    for (int kc = 0; kc < 8; kc++) {
        f16x8 ah[4];
#pragma unroll
        for (int rt = 0; rt < 4; rt++)
            ah[rt] = *(const f16x8*)(pf + (rt * 8 + kc) * 512 + L * 8);
#pragma unroll
        for (int qt = 0; qt < 8; qt++) {
            f16x8 bh = *(const f16x8*)(yb + ((size_t)kc * 32 + w * 8 + qt) * 512 + L * 8);
#pragma unroll
            for (int rt = 0; rt < 4; rt++)
                sc[rt][qt] = __builtin_amdgcn_mfma_f32_16x16x32_f16(ah[rt], bh, sc[rt][qt], 0, 0, 0);
        }
    }

    // ---- Phase B: fused softmax. Per-wave max + per-wave sum(exp(.-pm)), one
    // cross-wave combine: m=max pm_j, S=sum ps_j*exp(pm_j-m), alpha=e*exp(pm-m)/S.
    float* red  = (float*)lds;       // [64][4] partial max (x-frag region dead)
    float* red2 = red + 256;         // [64][4] partial sum
    float pmv[4][4], scl[4][4];
#pragma unroll
    for (int rt = 0; rt < 4; rt++)
#pragma unroll
        for (int r = 0; r < 4; r++) {
            float pm = sc[rt][0][r];
#pragma unroll
            for (int qt = 1; qt < 8; qt++) pm = fmaxf(pm, sc[rt][qt][r]);
#pragma unroll
            for (int mask = 1; mask <= 8; mask <<= 1) pm = fmaxf(pm, __shfl_xor(pm, mask));
            float ps = 0.f;
#pragma unroll
            for (int qt = 0; qt < 8; qt++) {
                float e = __expf(sc[rt][qt][r] - pm);
                sc[rt][qt][r] = e;
                ps += e;
            }
#pragma unroll
            for (int mask = 1; mask <= 8; mask <<= 1) ps += __shfl_xor(ps, mask);
            pmv[rt][r] = pm;
            if (c == 0) {
                int row = rt * 16 + quad * 4 + r;
                red[row * 4 + w]  = pm;
                red2[row * 4 + w] = ps;
            }
        }
    __syncthreads();                 // partials visible (waves exit A at own pace first)
#pragma unroll
    for (int rt = 0; rt < 4; rt++)
#pragma unroll
        for (int r = 0; r < 4; r++) {
            int row = rt * 16 + quad * 4 + r;
            float m0f = fmaxf(fmaxf(red[row * 4], red[row * 4 + 1]),
                              fmaxf(red[row * 4 + 2], red[row * 4 + 3]));
            float S = red2[row * 4] * __expf(red[row * 4] - m0f)
                    + red2[row * 4 + 1] * __expf(red[row * 4 + 1] - m0f)
                    + red2[row * 4 + 2] * __expf(red[row * 4 + 2] - m0f)
                    + red2[row * 4 + 3] * __expf(red[row * 4 + 3] - m0f);
            scl[rt][r] = __expf(pmv[rt][r] - m0f) / S;
        }
    __syncthreads();                 // red reads done before alpha overwrites

    // alpha (f16) -> LDS [0,32768): [64 rows][512 q], xor-swizzled 8-elem chunks
#pragma unroll
    for (int rt = 0; rt < 4; rt++)
#pragma unroll
        for (int r = 0; r < 4; r++) {
            int m_loc = rt * 16 + quad * 4 + r;
            int swz = m_loc & 7;
            float iv = scl[rt][r];
#pragma unroll
            for (int qt = 0; qt < 8; qt++) {
                int q = w * 128 + qt * 16 + c;
                lds[m_loc * 512 + (((q >> 3) ^ swz) << 3) + (c & 7)] = f2h(sc[rt][qt][r] * iv);
            }
        }
    __syncthreads();

    // ---- Phase C: out = alpha(LDS) @ yf(global). wave w = d-quarter, full q, ----
    // 4 MFMA per yf load.
    f32x4 o[4][4];
#pragma unroll
    for (int rt = 0; rt < 4; rt++)
#pragma unroll
        for (int dt = 0; dt < 4; dt++) o[rt][dt] = (f32x4)0.f;
    const int swzA = c & 7;          // (rt*16+c)&7 == c&7
    for (int kcq = 0; kcq < 16; kcq++) {
        int chunk = kcq * 4 + quad;
        f16x8 af[4];
#pragma unroll
        for (int rt = 0; rt < 4; rt++)
            af[rt] = *(const f16x8*)(lds + (rt * 16 + c) * 512 + ((chunk ^ swzA) << 3));
        const ushort* ybf = yf + ((size_t)(b * 256 + kcq * 16 + w * 4)) * 512;
#pragma unroll
        for (int dt = 0; dt < 4; dt++) {
            f16x8 bfr = *(const f16x8*)(ybf + dt * 512 + L * 8);
#pragma unroll
            for (int rt = 0; rt < 4; rt++)
                o[rt][dt] = __builtin_amdgcn_mfma_f32_16x16x32_f16(af[rt], bfr, o[rt][dt], 0, 0, 0);
        }
    }

    // ---- direct store (wave owns d-quarter w, all 64 rows) ----
#pragma unroll
    for (int rt = 0; rt < 4; rt++)
#pragma unroll
        for (int dt = 0; dt < 4; dt++)
#pragma unroll
            for (int r = 0; r < 4; r++) {
                int row = rt * 16 + quad * 4 + r;
                out[(size_t)(b * LP_ + m0 + row) * 256 + w * 64 + dt * 16 + c] =
                    o[rt][dt][r];
            }
}

extern "C" void kernel_launch(void* const* d_in, const int* in_sizes, int n_in,
                              void* d_out, int out_size, void* d_ws, size_t ws_size,
                              hipStream_t stream) {
    const float* x    = (const float*)d_in[0];
    const float* y    = (const float*)d_in[1];
    const float* W    = (const float*)d_in[2];
    const float* bias = (const float*)d_in[3];
    float* out = (float*)d_out;

    char* ws = (char*)d_ws;
    size_t off = 0;
    ushort* Whf = (ushort*)(ws + off); off += (size_t)D_ * D_ * 2;          // 128KB
    ushort* yfb = (ushort*)(ws + off); off += (size_t)B_ * D_ * LQ_ * 2;    // 8MB
    ushort* ypf = (ushort*)(ws + off); off += (size_t)B_ * LQ_ * D_ * 2;    // 8MB

    k_prep<<<768, 256, 0, stream>>>(W, y, Whf, yfb);
    k_proj<<<256, 256, 0, stream>>>(y, Whf, bias, ypf);
    k_attn<<<B_ * 32, 256, 0, stream>>>(x, Whf, bias, ypf, yfb, out);
}